// Round 8
// baseline (175.654 us; speedup 1.0000x reference)
//
#include <hip/hip_runtime.h>
#include <hip/hip_bf16.h>

#define SELU_L 1.0507009873554805f
#define SELU_A 1.6732632423543772f

typedef float  floatx4 __attribute__((ext_vector_type(4)));
typedef short  bf16x8  __attribute__((ext_vector_type(8)));

__device__ __forceinline__ float selu(float x) {
    return x > 0.f ? SELU_L * x : SELU_L * SELU_A * (expf(x) - 1.f);
}

__device__ __forceinline__ float fast_rcp(float x) {
    return __builtin_amdgcn_rcpf(x);
}

__device__ __forceinline__ unsigned short bf16_rne(float f) {
    unsigned int u = __float_as_uint(f);
    u += 0x7fffu + ((u >> 16) & 1u);
    return (unsigned short)(u >> 16);
}

// ---------------- Kernel P: split x|w into bf16 hi/lo planes, K-pad to 800 --
// planes: [8320][800] ushort; rows 0..8191 = x, 8192..8319 = w; k 784..799 = 0.
// Also zeroes the stat accumulators.
__global__ __launch_bounds__(256) void convert_split_pad(
    const float* __restrict__ x, const float* __restrict__ w,
    ushort* __restrict__ hi, ushort* __restrict__ lo, double* __restrict__ accs)
{
    if (blockIdx.x == 0 && threadIdx.x < 64) {
        for (int i = threadIdx.x; i < 257; i += 64) accs[i] = 0.0;
    }

    constexpr size_t NX4  = (size_t)8192 * 196;   // x float4 count (784/4=196)
    constexpr size_t TOT4 = (size_t)8320 * 196;
    const size_t tid0 = (size_t)blockIdx.x * 256 + threadIdx.x;
    const size_t step = (size_t)gridDim.x * 256;

    for (size_t i4 = tid0; i4 < TOT4; i4 += step) {
        float4 v = (i4 < NX4) ? reinterpret_cast<const float4*>(x)[i4]
                              : reinterpret_cast<const float4*>(w)[i4 - NX4];
        ushort4 h, l;
        h.x = bf16_rne(v.x); h.y = bf16_rne(v.y); h.z = bf16_rne(v.z); h.w = bf16_rne(v.w);
        float4 hf = make_float4(__uint_as_float((unsigned)h.x << 16),
                                __uint_as_float((unsigned)h.y << 16),
                                __uint_as_float((unsigned)h.z << 16),
                                __uint_as_float((unsigned)h.w << 16));
        l.x = bf16_rne(v.x - hf.x); l.y = bf16_rne(v.y - hf.y);
        l.z = bf16_rne(v.z - hf.z); l.w = bf16_rne(v.w - hf.w);
        const size_t row = i4 / 196, k4 = i4 % 196;
        const size_t dst = (row * 800 + k4 * 4) / 4;      // ushort4 index
        reinterpret_cast<ushort4*>(hi)[dst] = h;
        reinterpret_cast<ushort4*>(lo)[dst] = l;
    }

    // zero the K-pad region k in [784, 800) for all 8320 rows
    constexpr size_t PAD4 = (size_t)8320 * 4;             // ushort4 count
    const ushort4 z4 = make_ushort4(0, 0, 0, 0);
    for (size_t p = tid0; p < PAD4; p += step) {
        const size_t row = p >> 2, j = p & 3;
        const size_t dst = (row * 800 + 784 + j * 4) / 4;
        reinterpret_cast<ushort4*>(hi)[dst] = z4;
        reinterpret_cast<ushort4*>(lo)[dst] = z4;
    }
}

// ---------------- Kernel A': o1 = selu(x @ w^T + b) via split-bf16 MFMA -----
// Branch-free 25-iter K-loop over padded K=800. Single pass (probe removed).
__global__ __launch_bounds__(256) void gemm1_mfma(
    const ushort* __restrict__ hi, const ushort* __restrict__ lo,
    const float* __restrict__ b, float* __restrict__ o1)
{
    const int t    = threadIdx.x;
    const int lane = t & 63;
    const int wid  = blockIdx.x * 4 + (t >> 6);
    const int rt   = wid >> 3;        // 0..511
    const int ct   = wid & 7;         // 0..7
    const int lr   = lane & 15;
    const int lk   = lane >> 4;       // k-group 0..3

    const size_t arow = (size_t)(rt * 16 + lr) * 800 + lk * 8;
    const size_t brow = (size_t)(8192 + ct * 16 + lr) * 800 + lk * 8;
    const ushort* pah = hi + arow;
    const ushort* pal = lo + arow;
    const ushort* pbh = hi + brow;
    const ushort* pbl = lo + brow;

    floatx4 acc = {};
#pragma unroll 2
    for (int k0 = 0; k0 < 800; k0 += 32) {
        bf16x8 ahi = *reinterpret_cast<const bf16x8*>(pah + k0);
        bf16x8 alo = *reinterpret_cast<const bf16x8*>(pal + k0);
        bf16x8 bhi = *reinterpret_cast<const bf16x8*>(pbh + k0);
        bf16x8 blo = *reinterpret_cast<const bf16x8*>(pbl + k0);
        acc = __builtin_amdgcn_mfma_f32_16x16x32_bf16(alo, bhi, acc, 0, 0, 0);
        acc = __builtin_amdgcn_mfma_f32_16x16x32_bf16(ahi, blo, acc, 0, 0, 0);
        acc = __builtin_amdgcn_mfma_f32_16x16x32_bf16(ahi, bhi, acc, 0, 0, 0);
    }

    // C/D layout (m89): col = lane&15, row = (lane>>4)*4 + reg
    const int col  = ct * 16 + lr;
    const float bias = b[col];
#pragma unroll
    for (int j = 0; j < 4; ++j) {
        const int row = rt * 16 + lk * 4 + j;
        o1[(size_t)row * 128 + col] = selu(acc[j] + bias);
    }
}

// ---------------- Kernel B: per-column sum / sumsq --------------------------
__global__ __launch_bounds__(256) void bn_stats(
    const float* __restrict__ o1, double* __restrict__ sums, double* __restrict__ sumsq)
{
    const int t   = threadIdx.x;
    const int col = t % 128;
    const int rh  = t / 128;
    const int base = blockIdx.x * 64;
    float s = 0.f, s2 = 0.f;
    for (int r = rh; r < 64; r += 2) {
        float v = o1[(size_t)(base + r) * 128 + col];
        s += v;
        s2 = fmaf(v, v, s2);
    }
    __shared__ float sh[256], sh2[256];
    sh[t] = s; sh2[t] = s2;
    __syncthreads();
    if (rh == 0) {
        s  = sh[t] + sh[t + 128];
        s2 = sh2[t] + sh2[t + 128];
        atomicAdd(&sums[col],  (double)s);
        atomicAdd(&sumsq[col], (double)s2);
    }
}

// ---------------- Kernel C: BN normalize + fc2 + selu -----------------------
__global__ __launch_bounds__(256) void bn_fc2_selu(
    const float* __restrict__ o1, const double* __restrict__ sums, const double* __restrict__ sumsq,
    const float* __restrict__ gamma, const float* __restrict__ beta,
    const float* __restrict__ fc2w, const float* __restrict__ fc2b,
    float* __restrict__ o_out, float4* __restrict__ packed)
{
    const int wave = threadIdx.x >> 6;
    const int lane = threadIdx.x & 63;
    const int row  = blockIdx.x * 4 + wave;

    float d0 = 0.f, d1 = 0.f;
#pragma unroll
    for (int half = 0; half < 2; ++half) {
        const int col = lane + half * 64;
        const float mu  = (float)(sums[col]  * (1.0 / 8192.0));
        const float ex2 = (float)(sumsq[col] * (1.0 / 8192.0));
        const float var = ex2 - mu * mu;
        const float inv = rsqrtf(var + 1e-5f);
        const float v = (o1[(size_t)row * 128 + col] - mu) * inv * gamma[col] + beta[col];
        d0 = fmaf(v, fc2w[col],       d0);
        d1 = fmaf(v, fc2w[128 + col], d1);
    }
#pragma unroll
    for (int off = 32; off >= 1; off >>= 1) {
        d0 += __shfl_down(d0, off);
        d1 += __shfl_down(d1, off);
    }
    if (lane == 0) {
        const float y0 = selu(d0 + fc2b[0]);
        const float y1 = selu(d1 + fc2b[1]);
        o_out[(size_t)row * 2 + 0] = y0;
        o_out[(size_t)row * 2 + 1] = y1;
        packed[row] = make_float4(y0, y1, y0 * y0 + y1 * y1, 0.f);
    }
}

// ---------------- Kernel D: denom = 2 * sum_{i<j} 1/(1+dis) -----------------
__global__ __launch_bounds__(256) void denom_reduce(
    const float4* __restrict__ packed, double* __restrict__ denom)
{
    const int rb = blockIdx.x * 64;
    const int cb = blockIdx.y * 1024;
    if (cb + 1024 <= rb) return;            // whole block has j < i -> no pairs

    const int t = threadIdx.x;
    const bool full = (cb >= rb + 64);      // whole block has j > i

    float4 cd[4];
#pragma unroll
    for (int u = 0; u < 4; ++u) cd[u] = packed[cb + t + u * 256];

    float accf = 0.f;
#pragma unroll 4
    for (int r = 0; r < 64; ++r) {
        const int i = rb + r;
        const float4 pi = packed[i];        // uniform address -> scalar load
#pragma unroll
        for (int u = 0; u < 4; ++u) {
            float dis = pi.z + cd[u].z - 2.f * fmaf(pi.x, cd[u].x, pi.y * cd[u].y);
            dis = fmaxf(dis, 0.f);
            float f = fast_rcp(1.f + dis);
            if (!full) {
                const int j = cb + t + u * 256;
                f = (j > i) ? f : 0.f;
            }
            accf += f;
        }
    }
#pragma unroll
    for (int off = 32; off >= 1; off >>= 1) accf += __shfl_down(accf, off);
    __shared__ double wsum[4];
    const int wave = t >> 6, lane = t & 63;
    if (lane == 0) wsum[wave] = (double)accf;
    __syncthreads();
    if (t == 0) {
        double v = wsum[0] + wsum[1] + wsum[2] + wsum[3];
        atomicAdd(denom, 2.0 * v);          // full denom = 2 * sum_{i<j}
    }
}

// ---------------- Kernel E: qij = inv_denom / (1 + dis), PLAIN float4 stores
// *** nt removed; launched TWICE this round as an attribution probe (stores
//     are idempotent -> deterministic output). ***
__global__ __launch_bounds__(256) void qij_write(
    const float4* __restrict__ packed, const double* __restrict__ denom,
    float* __restrict__ qij)
{
    const int t  = threadIdx.x;
    const int cb = blockIdx.y * 1024;

    float4 cd[4];
#pragma unroll
    for (int u = 0; u < 4; ++u) cd[u] = packed[cb + t * 4 + u];

    const float inv = (float)(1.0 / denom[0]);

    const int rb = blockIdx.x * 32;
#pragma unroll 4
    for (int r = 0; r < 32; ++r) {
        const int i = rb + r;
        const float4 pi = packed[i];        // uniform address -> scalar load
        floatx4 q;
#pragma unroll
        for (int u = 0; u < 4; ++u) {
            float dis = pi.z + cd[u].z - 2.f * fmaf(pi.x, cd[u].x, pi.y * cd[u].y);
            dis = fmaxf(dis, 0.f);
            q[u] = inv * fast_rcp(1.f + dis);
        }
        *reinterpret_cast<floatx4*>(&qij[(size_t)i * 8192 + cb + t * 4]) = q;
    }
}

// ---------------------------------------------------------------------------
extern "C" void kernel_launch(void* const* d_in, const int* in_sizes, int n_in,
                              void* d_out, int out_size, void* d_ws, size_t ws_size,
                              hipStream_t stream)
{
    const float* x      = (const float*)d_in[0];
    const float* fc_w   = (const float*)d_in[1];
    const float* fc_b   = (const float*)d_in[2];
    const float* gamma  = (const float*)d_in[3];
    const float* beta   = (const float*)d_in[4];
    const float* fc2_w  = (const float*)d_in[5];
    const float* fc2_b  = (const float*)d_in[6];

    constexpr int N = 8192;

    float* qij   = (float*)d_out;                          // [N, N]
    float* o_out = (float*)d_out + (size_t)N * N;          // [N, 2]

    char* ws = (char*)d_ws;
    constexpr size_t O1_OFF      = 0;                         // 4 MB
    constexpr size_t ACC_OFF     = (size_t)N * 128 * 4;       // 257 doubles
    constexpr size_t PACKED_OFF  = ACC_OFF + 4096;            // 128 KB
    constexpr size_t HI_OFF      = PACKED_OFF + (size_t)N * 16;
    constexpr size_t PLANE_BYTES = (size_t)8320 * 800 * 2;    // 13.3 MB
    constexpr size_t PLANE_PAD   = ((PLANE_BYTES + 63) / 64) * 64;
    constexpr size_t LO_OFF      = HI_OFF + PLANE_PAD;

    float*  o1     = (float*)(ws + O1_OFF);
    double* accs   = (double*)(ws + ACC_OFF);              // sums|sumsq|denom
    double* sums   = accs;
    double* sumsq  = accs + 128;
    double* denom  = accs + 256;
    float4* packed = (float4*)(ws + PACKED_OFF);
    ushort* hi     = (ushort*)(ws + HI_OFF);
    ushort* lo     = (ushort*)(ws + LO_OFF);

    // P: split x|w into bf16 hi/lo planes (K padded to 800), zero accs
    convert_split_pad<<<2048, 256, 0, stream>>>(x, fc_w, hi, lo, accs);

    // A': o1 = selu(x @ fc_w^T + fc_b) via 3-pass split-bf16 MFMA
    gemm1_mfma<<<1024, 256, 0, stream>>>(hi, lo, fc_b, o1);

    // B: column stats
    bn_stats<<<N / 64, 256, 0, stream>>>(o1, sums, sumsq);

    // C: normalize + fc2 + selu -> o_out, packed
    bn_fc2_selu<<<N / 4, 256, 0, stream>>>(o1, sums, sumsq, gamma, beta, fc2_w, fc2_b, o_out, packed);

    // D: denom = 2 * sum_{i<j} 1/(1+dis)
    denom_reduce<<<dim3(N / 64, N / 1024), 256, 0, stream>>>(packed, denom);

    // E: qij = (1/denom) / (1 + dis)  [launched 2x: attribution probe]
    qij_write<<<dim3(N / 32, N / 1024), 256, 0, stream>>>(packed, denom, qij);
    qij_write<<<dim3(N / 32, N / 1024), 256, 0, stream>>>(packed, denom, qij);
}

// Round 9
// 123.818 us; speedup vs baseline: 1.4186x; 1.4186x over previous
//
#include <hip/hip_runtime.h>
#include <hip/hip_bf16.h>

#define SELU_L 1.0507009873554805f
#define SELU_A 1.6732632423543772f

typedef float  floatx4 __attribute__((ext_vector_type(4)));
typedef short  bf16x8  __attribute__((ext_vector_type(8)));

__device__ __forceinline__ float selu(float x) {
    return x > 0.f ? SELU_L * x : SELU_L * SELU_A * (expf(x) - 1.f);
}

__device__ __forceinline__ float fast_rcp(float x) {
    return __builtin_amdgcn_rcpf(x);
}

__device__ __forceinline__ unsigned short bf16_rne(float f) {
    unsigned int u = __float_as_uint(f);
    u += 0x7fffu + ((u >> 16) & 1u);
    return (unsigned short)(u >> 16);
}

// ---------------- Kernel P: split x|w into bf16 hi/lo planes, K-pad to 800 --
// planes: [8320][800] ushort; rows 0..8191 = x, 8192..8319 = w; k 784..799 = 0.
// Also zeroes the stat accumulators.
__global__ __launch_bounds__(256) void convert_split_pad(
    const float* __restrict__ x, const float* __restrict__ w,
    ushort* __restrict__ hi, ushort* __restrict__ lo, double* __restrict__ accs)
{
    if (blockIdx.x == 0 && threadIdx.x < 64) {
        for (int i = threadIdx.x; i < 257; i += 64) accs[i] = 0.0;
    }

    constexpr size_t NX4  = (size_t)8192 * 196;   // x float4 count (784/4=196)
    constexpr size_t TOT4 = (size_t)8320 * 196;
    const size_t tid0 = (size_t)blockIdx.x * 256 + threadIdx.x;
    const size_t step = (size_t)gridDim.x * 256;

    for (size_t i4 = tid0; i4 < TOT4; i4 += step) {
        float4 v = (i4 < NX4) ? reinterpret_cast<const float4*>(x)[i4]
                              : reinterpret_cast<const float4*>(w)[i4 - NX4];
        ushort4 h, l;
        h.x = bf16_rne(v.x); h.y = bf16_rne(v.y); h.z = bf16_rne(v.z); h.w = bf16_rne(v.w);
        float4 hf = make_float4(__uint_as_float((unsigned)h.x << 16),
                                __uint_as_float((unsigned)h.y << 16),
                                __uint_as_float((unsigned)h.z << 16),
                                __uint_as_float((unsigned)h.w << 16));
        l.x = bf16_rne(v.x - hf.x); l.y = bf16_rne(v.y - hf.y);
        l.z = bf16_rne(v.z - hf.z); l.w = bf16_rne(v.w - hf.w);
        const size_t row = i4 / 196, k4 = i4 % 196;
        const size_t dst = (row * 800 + k4 * 4) / 4;      // ushort4 index
        reinterpret_cast<ushort4*>(hi)[dst] = h;
        reinterpret_cast<ushort4*>(lo)[dst] = l;
    }

    // zero the K-pad region k in [784, 800) for all 8320 rows
    constexpr size_t PAD4 = (size_t)8320 * 4;             // ushort4 count
    const ushort4 z4 = make_ushort4(0, 0, 0, 0);
    for (size_t p = tid0; p < PAD4; p += step) {
        const size_t row = p >> 2, j = p & 3;
        const size_t dst = (row * 800 + 784 + j * 4) / 4;
        reinterpret_cast<ushort4*>(hi)[dst] = z4;
        reinterpret_cast<ushort4*>(lo)[dst] = z4;
    }
}

// ---------------- Kernel A': o1 = selu(x @ w^T + b) via split-bf16 MFMA -----
// Branch-free 25-iter K-loop over padded K=800. Fused column stats:
// per-wave 16-row column sums via shfl_xor reduce + f64 atomics.
__global__ __launch_bounds__(256) void gemm1_mfma_stats(
    const ushort* __restrict__ hi, const ushort* __restrict__ lo,
    const float* __restrict__ b, float* __restrict__ o1,
    double* __restrict__ sums, double* __restrict__ sumsq)
{
    const int t    = threadIdx.x;
    const int lane = t & 63;
    const int wid  = blockIdx.x * 4 + (t >> 6);
    const int rt   = wid >> 3;        // 0..511
    const int ct   = wid & 7;         // 0..7
    const int lr   = lane & 15;
    const int lk   = lane >> 4;       // k-group 0..3

    const size_t arow = (size_t)(rt * 16 + lr) * 800 + lk * 8;
    const size_t brow = (size_t)(8192 + ct * 16 + lr) * 800 + lk * 8;
    const ushort* pah = hi + arow;
    const ushort* pal = lo + arow;
    const ushort* pbh = hi + brow;
    const ushort* pbl = lo + brow;

    floatx4 acc = {};
#pragma unroll 2
    for (int k0 = 0; k0 < 800; k0 += 32) {
        bf16x8 ahi = *reinterpret_cast<const bf16x8*>(pah + k0);
        bf16x8 alo = *reinterpret_cast<const bf16x8*>(pal + k0);
        bf16x8 bhi = *reinterpret_cast<const bf16x8*>(pbh + k0);
        bf16x8 blo = *reinterpret_cast<const bf16x8*>(pbl + k0);
        acc = __builtin_amdgcn_mfma_f32_16x16x32_bf16(alo, bhi, acc, 0, 0, 0);
        acc = __builtin_amdgcn_mfma_f32_16x16x32_bf16(ahi, blo, acc, 0, 0, 0);
        acc = __builtin_amdgcn_mfma_f32_16x16x32_bf16(ahi, bhi, acc, 0, 0, 0);
    }

    // C/D layout (m89): col = lane&15, row = (lane>>4)*4 + reg
    const int col  = ct * 16 + lr;
    const float bias = b[col];
    float s = 0.f, s2 = 0.f;
#pragma unroll
    for (int j = 0; j < 4; ++j) {
        const int row = rt * 16 + lk * 4 + j;
        const float val = selu(acc[j] + bias);
        o1[(size_t)row * 128 + col] = val;
        s += val;
        s2 = fmaf(val, val, s2);
    }
    // reduce the wave's 16 rows for this column (lanes lr, lr+16, lr+32, lr+48)
    s  += __shfl_xor(s, 16);   s  += __shfl_xor(s, 32);
    s2 += __shfl_xor(s2, 16);  s2 += __shfl_xor(s2, 32);
    if (lane < 16) {
        atomicAdd(&sums[col],  (double)s);
        atomicAdd(&sumsq[col], (double)s2);
    }
}

// ---------------- Kernel C: BN normalize + fc2 + selu -----------------------
__global__ __launch_bounds__(256) void bn_fc2_selu(
    const float* __restrict__ o1, const double* __restrict__ sums, const double* __restrict__ sumsq,
    const float* __restrict__ gamma, const float* __restrict__ beta,
    const float* __restrict__ fc2w, const float* __restrict__ fc2b,
    float* __restrict__ o_out, float4* __restrict__ packed)
{
    const int wave = threadIdx.x >> 6;
    const int lane = threadIdx.x & 63;
    const int row  = blockIdx.x * 4 + wave;

    float d0 = 0.f, d1 = 0.f;
#pragma unroll
    for (int half = 0; half < 2; ++half) {
        const int col = lane + half * 64;
        const float mu  = (float)(sums[col]  * (1.0 / 8192.0));
        const float ex2 = (float)(sumsq[col] * (1.0 / 8192.0));
        const float var = ex2 - mu * mu;
        const float inv = rsqrtf(var + 1e-5f);
        const float v = (o1[(size_t)row * 128 + col] - mu) * inv * gamma[col] + beta[col];
        d0 = fmaf(v, fc2w[col],       d0);
        d1 = fmaf(v, fc2w[128 + col], d1);
    }
#pragma unroll
    for (int off = 32; off >= 1; off >>= 1) {
        d0 += __shfl_down(d0, off);
        d1 += __shfl_down(d1, off);
    }
    if (lane == 0) {
        const float y0 = selu(d0 + fc2b[0]);
        const float y1 = selu(d1 + fc2b[1]);
        o_out[(size_t)row * 2 + 0] = y0;
        o_out[(size_t)row * 2 + 1] = y1;
        packed[row] = make_float4(y0, y1, y0 * y0 + y1 * y1, 0.f);
    }
}

// ---------------- Kernel D: denom = 2 * sum_{i<j} 1/(1+dis) -----------------
__global__ __launch_bounds__(256) void denom_reduce(
    const float4* __restrict__ packed, double* __restrict__ denom)
{
    const int rb = blockIdx.x * 64;
    const int cb = blockIdx.y * 1024;
    if (cb + 1024 <= rb) return;            // whole block has j < i -> no pairs

    const int t = threadIdx.x;
    const bool full = (cb >= rb + 64);      // whole block has j > i

    float4 cd[4];
#pragma unroll
    for (int u = 0; u < 4; ++u) cd[u] = packed[cb + t + u * 256];

    float accf = 0.f;
#pragma unroll 4
    for (int r = 0; r < 64; ++r) {
        const int i = rb + r;
        const float4 pi = packed[i];        // uniform address -> scalar load
#pragma unroll
        for (int u = 0; u < 4; ++u) {
            float dis = pi.z + cd[u].z - 2.f * fmaf(pi.x, cd[u].x, pi.y * cd[u].y);
            dis = fmaxf(dis, 0.f);
            float f = fast_rcp(1.f + dis);
            if (!full) {
                const int j = cb + t + u * 256;
                f = (j > i) ? f : 0.f;
            }
            accf += f;
        }
    }
#pragma unroll
    for (int off = 32; off >= 1; off >>= 1) accf += __shfl_down(accf, off);
    __shared__ double wsum[4];
    const int wave = t >> 6, lane = t & 63;
    if (lane == 0) wsum[wave] = (double)accf;
    __syncthreads();
    if (t == 0) {
        double v = wsum[0] + wsum[1] + wsum[2] + wsum[3];
        atomicAdd(denom, 2.0 * v);          // full denom = 2 * sum_{i<j}
    }
}

// ---------------- Kernel E: qij = inv_denom / (1 + dis) ---------------------
// grid (128, 8): 64 rows x 1024 cols per block. Row data staged once in LDS,
// read back as wave-uniform broadcast ds_read_b128 (conflict-free).
__global__ __launch_bounds__(256) void qij_write(
    const float4* __restrict__ packed, const double* __restrict__ denom,
    float* __restrict__ qij)
{
    __shared__ float4 rowsh[64];
    const int t  = threadIdx.x;
    const int cb = blockIdx.y * 1024;
    const int rb = blockIdx.x * 64;

    float4 cd[4];
#pragma unroll
    for (int u = 0; u < 4; ++u) cd[u] = packed[cb + t * 4 + u];
    if (t < 64) rowsh[t] = packed[rb + t];

    const float inv = (float)(1.0 / denom[0]);
    __syncthreads();

#pragma unroll 2
    for (int r = 0; r < 64; ++r) {
        const float4 pi = rowsh[r];         // uniform -> LDS broadcast
        floatx4 q;
#pragma unroll
        for (int u = 0; u < 4; ++u) {
            float dis = pi.z + cd[u].z - 2.f * fmaf(pi.x, cd[u].x, pi.y * cd[u].y);
            dis = fmaxf(dis, 0.f);
            q[u] = inv * fast_rcp(1.f + dis);
        }
        *reinterpret_cast<floatx4*>(&qij[(size_t)(rb + r) * 8192 + cb + t * 4]) = q;
    }
}

// ---------------------------------------------------------------------------
extern "C" void kernel_launch(void* const* d_in, const int* in_sizes, int n_in,
                              void* d_out, int out_size, void* d_ws, size_t ws_size,
                              hipStream_t stream)
{
    const float* x      = (const float*)d_in[0];
    const float* fc_w   = (const float*)d_in[1];
    const float* fc_b   = (const float*)d_in[2];
    const float* gamma  = (const float*)d_in[3];
    const float* beta   = (const float*)d_in[4];
    const float* fc2_w  = (const float*)d_in[5];
    const float* fc2_b  = (const float*)d_in[6];

    constexpr int N = 8192;

    float* qij   = (float*)d_out;                          // [N, N]
    float* o_out = (float*)d_out + (size_t)N * N;          // [N, 2]

    char* ws = (char*)d_ws;
    constexpr size_t O1_OFF      = 0;                         // 4 MB
    constexpr size_t ACC_OFF     = (size_t)N * 128 * 4;       // 257 doubles
    constexpr size_t PACKED_OFF  = ACC_OFF + 4096;            // 128 KB
    constexpr size_t HI_OFF      = PACKED_OFF + (size_t)N * 16;
    constexpr size_t PLANE_BYTES = (size_t)8320 * 800 * 2;    // 13.3 MB
    constexpr size_t PLANE_PAD   = ((PLANE_BYTES + 63) / 64) * 64;
    constexpr size_t LO_OFF      = HI_OFF + PLANE_PAD;

    float*  o1     = (float*)(ws + O1_OFF);
    double* accs   = (double*)(ws + ACC_OFF);              // sums|sumsq|denom
    double* sums   = accs;
    double* sumsq  = accs + 128;
    double* denom  = accs + 256;
    float4* packed = (float4*)(ws + PACKED_OFF);
    ushort* hi     = (ushort*)(ws + HI_OFF);
    ushort* lo     = (ushort*)(ws + LO_OFF);

    // P: split x|w into bf16 hi/lo planes (K padded to 800), zero accs
    convert_split_pad<<<2048, 256, 0, stream>>>(x, fc_w, hi, lo, accs);

    // A': o1 = selu(x @ fc_w^T + fc_b) via split-bf16 MFMA, fused column stats
    gemm1_mfma_stats<<<1024, 256, 0, stream>>>(hi, lo, fc_b, o1, sums, sumsq);

    // C: normalize + fc2 + selu -> o_out, packed
    bn_fc2_selu<<<N / 4, 256, 0, stream>>>(o1, sums, sumsq, gamma, beta, fc2_w, fc2_b, o_out, packed);

    // D: denom = 2 * sum_{i<j} 1/(1+dis)
    denom_reduce<<<dim3(N / 64, N / 1024), 256, 0, stream>>>(packed, denom);

    // E: qij = (1/denom) / (1 + dis)
    qij_write<<<dim3(N / 64, N / 1024), 256, 0, stream>>>(packed, denom, qij);
}

// Round 10
// 114.861 us; speedup vs baseline: 1.5293x; 1.0780x over previous
//
#include <hip/hip_runtime.h>
#include <hip/hip_bf16.h>

#define SELU_L 1.0507009873554805f
#define SELU_A 1.6732632423543772f

typedef float  floatx4 __attribute__((ext_vector_type(4)));
typedef short  bf16x8  __attribute__((ext_vector_type(8)));

__device__ __forceinline__ float selu(float x) {
    return x > 0.f ? SELU_L * x : SELU_L * SELU_A * (expf(x) - 1.f);
}

__device__ __forceinline__ float fast_rcp(float x) {
    return __builtin_amdgcn_rcpf(x);
}

__device__ __forceinline__ unsigned short bf16_rne(float f) {
    unsigned int u = __float_as_uint(f);
    u += 0x7fffu + ((u >> 16) & 1u);
    return (unsigned short)(u >> 16);
}

// convert 8 consecutive fp32 -> hi/lo bf16 planes (in registers)
__device__ __forceinline__ void cvt8(const float* __restrict__ p,
                                     bf16x8& h8, bf16x8& l8) {
    float4 v0 = *reinterpret_cast<const float4*>(p);
    float4 v1 = *reinterpret_cast<const float4*>(p + 4);
    float f[8] = {v0.x, v0.y, v0.z, v0.w, v1.x, v1.y, v1.z, v1.w};
#pragma unroll
    for (int j = 0; j < 8; ++j) {
        const unsigned short h = bf16_rne(f[j]);
        const float hf = __uint_as_float((unsigned)h << 16);
        const unsigned short l = bf16_rne(f[j] - hf);
        h8[j] = (short)h;
        l8[j] = (short)l;
    }
}

// ---------------- Kernel W: convert fc_w into bf16 hi/lo planes -------------
// whi/wlo: [128][800] ushort, cols 784..799 zero. Also zeroes accumulators.
__global__ __launch_bounds__(256) void convert_w_pad(
    const float* __restrict__ w, ushort* __restrict__ whi, ushort* __restrict__ wlo,
    double* __restrict__ accs)
{
    const int row = blockIdx.x;           // 0..127
    const int t   = threadIdx.x;
    if (row == 0 && t < 64) {
        for (int i = t; i < 257; i += 64) accs[i] = 0.0;
    }
    if (t < 196) {
        float4 v = reinterpret_cast<const float4*>(w + (size_t)row * 784)[t];
        ushort4 h, l;
        h.x = bf16_rne(v.x); h.y = bf16_rne(v.y); h.z = bf16_rne(v.z); h.w = bf16_rne(v.w);
        float4 hf = make_float4(__uint_as_float((unsigned)h.x << 16),
                                __uint_as_float((unsigned)h.y << 16),
                                __uint_as_float((unsigned)h.z << 16),
                                __uint_as_float((unsigned)h.w << 16));
        l.x = bf16_rne(v.x - hf.x); l.y = bf16_rne(v.y - hf.y);
        l.z = bf16_rne(v.z - hf.z); l.w = bf16_rne(v.w - hf.w);
        reinterpret_cast<ushort4*>(whi + (size_t)row * 800)[t] = h;
        reinterpret_cast<ushort4*>(wlo + (size_t)row * 800)[t] = l;
    } else if (t < 200) {
        const ushort4 z = make_ushort4(0, 0, 0, 0);
        reinterpret_cast<ushort4*>(whi + (size_t)row * 800)[t] = z;
        reinterpret_cast<ushort4*>(wlo + (size_t)row * 800)[t] = z;
    }
}

// ---------------- Kernel A: o1 = selu(x @ w^T + b), split-bf16 MFMA ---------
// x consumed directly in fp32; hi/lo split done IN REGISTERS (no x planes).
// wave -> 16x16 tile: rt = wid>>3, ct = wid&7. Fused column stats.
__global__ __launch_bounds__(256) void gemm1_mfma_stats(
    const float* __restrict__ x,
    const ushort* __restrict__ whi, const ushort* __restrict__ wlo,
    const float* __restrict__ b, float* __restrict__ o1,
    double* __restrict__ sums, double* __restrict__ sumsq)
{
    const int t    = threadIdx.x;
    const int lane = t & 63;
    const int wid  = blockIdx.x * 4 + (t >> 6);
    const int rt   = wid >> 3;        // 0..511
    const int ct   = wid & 7;         // 0..7
    const int lr   = lane & 15;
    const int lk   = lane >> 4;       // k-group 0..3

    const float*  px  = x   + (size_t)(rt * 16 + lr) * 784 + lk * 8;
    const ushort* pbh = whi + (size_t)(ct * 16 + lr) * 800 + lk * 8;
    const ushort* pbl = wlo + (size_t)(ct * 16 + lr) * 800 + lk * 8;

    floatx4 acc = {};
#pragma unroll 2
    for (int k0 = 0; k0 < 768; k0 += 32) {
        bf16x8 ahi, alo;
        cvt8(px + k0, ahi, alo);
        bf16x8 bhi = *reinterpret_cast<const bf16x8*>(pbh + k0);
        bf16x8 blo = *reinterpret_cast<const bf16x8*>(pbl + k0);
        acc = __builtin_amdgcn_mfma_f32_16x16x32_bf16(alo, bhi, acc, 0, 0, 0);
        acc = __builtin_amdgcn_mfma_f32_16x16x32_bf16(ahi, blo, acc, 0, 0, 0);
        acc = __builtin_amdgcn_mfma_f32_16x16x32_bf16(ahi, bhi, acc, 0, 0, 0);
    }
    {   // peeled K tail (k0 = 768): k >= 784 doesn't exist -> zero frags
        bf16x8 ahi = {}, alo = {};
        if (lk < 2) cvt8(px + 768, ahi, alo);
        bf16x8 bhi = *reinterpret_cast<const bf16x8*>(pbh + 768);
        bf16x8 blo = *reinterpret_cast<const bf16x8*>(pbl + 768);
        acc = __builtin_amdgcn_mfma_f32_16x16x32_bf16(alo, bhi, acc, 0, 0, 0);
        acc = __builtin_amdgcn_mfma_f32_16x16x32_bf16(ahi, blo, acc, 0, 0, 0);
        acc = __builtin_amdgcn_mfma_f32_16x16x32_bf16(ahi, bhi, acc, 0, 0, 0);
    }

    // C/D layout (m89): col = lane&15, row = (lane>>4)*4 + reg
    const int col  = ct * 16 + lr;
    const float bias = b[col];
    float s = 0.f, s2 = 0.f;
#pragma unroll
    for (int j = 0; j < 4; ++j) {
        const int row = rt * 16 + lk * 4 + j;
        const float val = selu(acc[j] + bias);
        o1[(size_t)row * 128 + col] = val;
        s += val;
        s2 = fmaf(val, val, s2);
    }
    // reduce the wave's 16 rows for this column
    s  += __shfl_xor(s, 16);   s  += __shfl_xor(s, 32);
    s2 += __shfl_xor(s2, 16);  s2 += __shfl_xor(s2, 32);
    if (lane < 16) {
        atomicAdd(&sums[col],  (double)s);
        atomicAdd(&sumsq[col], (double)s2);
    }
}

// ---------------- Kernel C: BN normalize + fc2 + selu -----------------------
__global__ __launch_bounds__(256) void bn_fc2_selu(
    const float* __restrict__ o1, const double* __restrict__ sums, const double* __restrict__ sumsq,
    const float* __restrict__ gamma, const float* __restrict__ beta,
    const float* __restrict__ fc2w, const float* __restrict__ fc2b,
    float* __restrict__ o_out, float4* __restrict__ packed)
{
    const int wave = threadIdx.x >> 6;
    const int lane = threadIdx.x & 63;
    const int row  = blockIdx.x * 4 + wave;

    float d0 = 0.f, d1 = 0.f;
#pragma unroll
    for (int half = 0; half < 2; ++half) {
        const int col = lane + half * 64;
        const float mu  = (float)(sums[col]  * (1.0 / 8192.0));
        const float ex2 = (float)(sumsq[col] * (1.0 / 8192.0));
        const float var = ex2 - mu * mu;
        const float inv = rsqrtf(var + 1e-5f);
        const float v = (o1[(size_t)row * 128 + col] - mu) * inv * gamma[col] + beta[col];
        d0 = fmaf(v, fc2w[col],       d0);
        d1 = fmaf(v, fc2w[128 + col], d1);
    }
#pragma unroll
    for (int off = 32; off >= 1; off >>= 1) {
        d0 += __shfl_down(d0, off);
        d1 += __shfl_down(d1, off);
    }
    if (lane == 0) {
        const float y0 = selu(d0 + fc2b[0]);
        const float y1 = selu(d1 + fc2b[1]);
        o_out[(size_t)row * 2 + 0] = y0;
        o_out[(size_t)row * 2 + 1] = y1;
        packed[row] = make_float4(y0, y1, y0 * y0 + y1 * y1, 0.f);
    }
}

// ---------------- Kernel D: denom = 2 * sum_{i<j} 1/(1+dis) -----------------
__global__ __launch_bounds__(256) void denom_reduce(
    const float4* __restrict__ packed, double* __restrict__ denom)
{
    const int rb = blockIdx.x * 64;
    const int cb = blockIdx.y * 1024;
    if (cb + 1024 <= rb) return;            // whole block has j < i -> no pairs

    const int t = threadIdx.x;
    const bool full = (cb >= rb + 64);      // whole block has j > i

    float4 cd[4];
#pragma unroll
    for (int u = 0; u < 4; ++u) cd[u] = packed[cb + t + u * 256];

    float accf = 0.f;
#pragma unroll 4
    for (int r = 0; r < 64; ++r) {
        const int i = rb + r;
        const float4 pi = packed[i];        // uniform address -> scalar load
#pragma unroll
        for (int u = 0; u < 4; ++u) {
            float dis = pi.z + cd[u].z - 2.f * fmaf(pi.x, cd[u].x, pi.y * cd[u].y);
            dis = fmaxf(dis, 0.f);
            float f = fast_rcp(1.f + dis);
            if (!full) {
                const int j = cb + t + u * 256;
                f = (j > i) ? f : 0.f;
            }
            accf += f;
        }
    }
#pragma unroll
    for (int off = 32; off >= 1; off >>= 1) accf += __shfl_down(accf, off);
    __shared__ double wsum[4];
    const int wave = t >> 6, lane = t & 63;
    if (lane == 0) wsum[wave] = (double)accf;
    __syncthreads();
    if (t == 0) {
        double v = wsum[0] + wsum[1] + wsum[2] + wsum[3];
        atomicAdd(denom, 2.0 * v);          // full denom = 2 * sum_{i<j}
    }
}

// ---------------- Kernel E: qij = inv_denom / (1 + dis) ---------------------
// grid (128, 8): 64 rows x 1024 cols per block. Row data staged in LDS,
// read back as wave-uniform broadcast (conflict-free).
__global__ __launch_bounds__(256) void qij_write(
    const float4* __restrict__ packed, const double* __restrict__ denom,
    float* __restrict__ qij)
{
    __shared__ float4 rowsh[64];
    const int t  = threadIdx.x;
    const int cb = blockIdx.y * 1024;
    const int rb = blockIdx.x * 64;

    float4 cd[4];
#pragma unroll
    for (int u = 0; u < 4; ++u) cd[u] = packed[cb + t * 4 + u];
    if (t < 64) rowsh[t] = packed[rb + t];

    const float inv = (float)(1.0 / denom[0]);
    __syncthreads();

#pragma unroll 2
    for (int r = 0; r < 64; ++r) {
        const float4 pi = rowsh[r];         // uniform -> LDS broadcast
        floatx4 q;
#pragma unroll
        for (int u = 0; u < 4; ++u) {
            float dis = pi.z + cd[u].z - 2.f * fmaf(pi.x, cd[u].x, pi.y * cd[u].y);
            dis = fmaxf(dis, 0.f);
            q[u] = inv * fast_rcp(1.f + dis);
        }
        *reinterpret_cast<floatx4*>(&qij[(size_t)(rb + r) * 8192 + cb + t * 4]) = q;
    }
}

// ---------------------------------------------------------------------------
extern "C" void kernel_launch(void* const* d_in, const int* in_sizes, int n_in,
                              void* d_out, int out_size, void* d_ws, size_t ws_size,
                              hipStream_t stream)
{
    const float* x      = (const float*)d_in[0];
    const float* fc_w   = (const float*)d_in[1];
    const float* fc_b   = (const float*)d_in[2];
    const float* gamma  = (const float*)d_in[3];
    const float* beta   = (const float*)d_in[4];
    const float* fc2_w  = (const float*)d_in[5];
    const float* fc2_b  = (const float*)d_in[6];

    constexpr int N = 8192;

    float* qij   = (float*)d_out;                          // [N, N]
    float* o_out = (float*)d_out + (size_t)N * N;          // [N, 2]

    char* ws = (char*)d_ws;
    constexpr size_t O1_OFF     = 0;                          // 4 MB
    constexpr size_t ACC_OFF    = (size_t)N * 128 * 4;        // 257 doubles
    constexpr size_t PACKED_OFF = ACC_OFF + 4096;             // 128 KB
    constexpr size_t WHI_OFF    = PACKED_OFF + (size_t)N * 16;
    constexpr size_t WPLANE     = ((size_t)128 * 800 * 2 + 63) / 64 * 64;
    constexpr size_t WLO_OFF    = WHI_OFF + WPLANE;

    float*  o1     = (float*)(ws + O1_OFF);
    double* accs   = (double*)(ws + ACC_OFF);              // sums|sumsq|denom
    double* sums   = accs;
    double* sumsq  = accs + 128;
    double* denom  = accs + 256;
    float4* packed = (float4*)(ws + PACKED_OFF);
    ushort* whi    = (ushort*)(ws + WHI_OFF);
    ushort* wlo    = (ushort*)(ws + WLO_OFF);

    // W: convert fc_w to bf16 hi/lo planes (padded to K=800), zero accs
    convert_w_pad<<<128, 256, 0, stream>>>(fc_w, whi, wlo, accs);

    // A: o1 = selu(x @ fc_w^T + fc_b), inline x split, fused column stats
    gemm1_mfma_stats<<<1024, 256, 0, stream>>>(x, whi, wlo, fc_b, o1, sums, sumsq);

    // C: normalize + fc2 + selu -> o_out, packed
    bn_fc2_selu<<<N / 4, 256, 0, stream>>>(o1, sums, sumsq, gamma, beta, fc2_w, fc2_b, o_out, packed);

    // D: denom = 2 * sum_{i<j} 1/(1+dis)
    denom_reduce<<<dim3(N / 64, N / 1024), 256, 0, stream>>>(packed, denom);

    // E: qij = (1/denom) / (1 + dis)
    qij_write<<<dim3(N / 64, N / 1024), 256, 0, stream>>>(packed, denom, qij);
}